// Round 8
// baseline (238.954 us; speedup 1.0000x reference)
//
#include <hip/hip_runtime.h>
#include <hip/hip_bf16.h>

#define NGROUP 256   // B * (SEQ/TG)
#define NSLOT  128   // experts * sets
#define TG     32    // tokens per group
#define DM     1024  // model dim
#define FF     32    // expert size

#define LSCALE     4096.0f
#define INV_LSCALE (1.0f / 4096.0f)

typedef unsigned int  uint;
typedef unsigned short ushort;
typedef __attribute__((ext_vector_type(4))) float f32x4;
typedef __attribute__((ext_vector_type(8))) short bf16x8;
typedef __attribute__((ext_vector_type(8))) _Float16 f16x8;

__device__ __forceinline__ ushort f2bf(float f) {
    uint u = __float_as_uint(f);
    u += 0x7FFFu + ((u >> 16) & 1u);   // RNE
    return (ushort)(u >> 16);
}
__device__ __forceinline__ uint pk2(float a, float b) {
    return (uint)f2bf(a) | ((uint)f2bf(b) << 16);
}

// ---------------------------------------------------------------------------
// K0: prep. (unchanged from v7)
//  blocks 0..255   : f1[d][es][f] -> f1F (bf16, MFMA-B FRAGMENT order)
//  blocks 256..767 : f2[es][f][d] -> f2T[es][d][f] bf16
//  blocks 768..775 : ctrl -> cFh/cFl fp16 split, fragment order
// ---------------------------------------------------------------------------
__global__ __launch_bounds__(256) void k_prep(
    const float* __restrict__ f1, const float* __restrict__ f2,
    const float* __restrict__ ctrl,
    ushort* __restrict__ f1F, ushort* __restrict__ f2T,
    ushort* __restrict__ cFh, ushort* __restrict__ cFl)
{
    __shared__ float Ltr[64 * 33];
    const int t = threadIdx.x;
    if (blockIdx.x < 256) {
        const int es = blockIdx.x >> 1;
        const int dh = blockIdx.x & 1;
        for (int d0 = dh * 512; d0 < dh * 512 + 512; d0 += 64) {
            const int dd = t >> 2, f0 = (t & 3) * 8;
            const float* src = f1 + (size_t)(d0 + dd) * 4096 + es * FF + f0;
            float4 a = *(const float4*)src;
            float4 b = *(const float4*)(src + 4);
            __syncthreads();
            float* Lp = &Ltr[dd * 33 + f0];
            Lp[0] = a.x; Lp[1] = a.y; Lp[2] = a.z; Lp[3] = a.w;
            Lp[4] = b.x; Lp[5] = b.y; Lp[6] = b.z; Lp[7] = b.w;
            __syncthreads();
            const int f = t & 31, koct = t >> 5;
            const int nt = f >> 4;
            const int kg = d0 + koct * 8;
            const int kslice = kg >> 5;
            const int lane2 = (f & 15) | (((kg >> 3) & 3) << 4);
            uint4 o;
            o.x = pk2(Ltr[(koct * 8 + 0) * 33 + f], Ltr[(koct * 8 + 1) * 33 + f]);
            o.y = pk2(Ltr[(koct * 8 + 2) * 33 + f], Ltr[(koct * 8 + 3) * 33 + f]);
            o.z = pk2(Ltr[(koct * 8 + 4) * 33 + f], Ltr[(koct * 8 + 5) * 33 + f]);
            o.w = pk2(Ltr[(koct * 8 + 6) * 33 + f], Ltr[(koct * 8 + 7) * 33 + f]);
            *(uint4*)(f1F + ((((size_t)es * 2 + nt) * 32 + kslice) * 64 + lane2) * 8) = o;
        }
    } else if (blockIdx.x < 768) {
        const int i2 = blockIdx.x - 256;
        const int es = i2 >> 2;
        const int dq = i2 & 3;
        for (int d0 = dq * 256; d0 < dq * 256 + 256; d0 += 64) {
            const int f = t >> 3, ds = (t & 7) * 8;
            const float* src = f2 + (size_t)es * (FF * DM) + f * DM + d0 + ds;
            float4 a = *(const float4*)src;
            float4 b = *(const float4*)(src + 4);
            __syncthreads();
            Ltr[(ds + 0) * 33 + f] = a.x; Ltr[(ds + 1) * 33 + f] = a.y;
            Ltr[(ds + 2) * 33 + f] = a.z; Ltr[(ds + 3) * 33 + f] = a.w;
            Ltr[(ds + 4) * 33 + f] = b.x; Ltr[(ds + 5) * 33 + f] = b.y;
            Ltr[(ds + 6) * 33 + f] = b.z; Ltr[(ds + 7) * 33 + f] = b.w;
            __syncthreads();
            const int dd = t >> 2, f0 = (t & 3) * 8;
            uint4 o;
            o.x = pk2(Ltr[dd * 33 + f0 + 0], Ltr[dd * 33 + f0 + 1]);
            o.y = pk2(Ltr[dd * 33 + f0 + 2], Ltr[dd * 33 + f0 + 3]);
            o.z = pk2(Ltr[dd * 33 + f0 + 4], Ltr[dd * 33 + f0 + 5]);
            o.w = pk2(Ltr[dd * 33 + f0 + 6], Ltr[dd * 33 + f0 + 7]);
            *(uint4*)(f2T + (size_t)es * (FF * DM) + (d0 + dd) * FF + f0) = o;
        }
    } else {
        const int base_o = ((blockIdx.x - 768) * 256 + t) * 8;
#pragma unroll
        for (int q = 0; q < 8; ++q) {
            const int o = base_o + q;
            const int lane = o & 63, ks = (o >> 6) & 31, nt = o >> 11;
            const int k = ks * 32 + ((lane >> 4) << 3);
            const int n = nt * 16 + (lane & 15);
            union { f16x8 v; _Float16 e[8]; } H, L;
#pragma unroll
            for (int j = 0; j < 8; ++j) {
                const float c = ctrl[(size_t)(k + j) * NSLOT + n];
                const _Float16 h = (_Float16)c;
                H.e[j] = h;
                L.e[j] = (_Float16)((c - (float)h) * LSCALE);
            }
            *(f16x8*)(cFh + (size_t)o * 8) = H.v;
            *(f16x8*)(cFl + (size_t)o * 8) = L.v;
        }
    }
}

// ---------------------------------------------------------------------------
// K1: SELF-CONTAINED logits + tie-broken argmax + fused x->bf16 cast.
// grid = 256 g x 2 nh (slot-halves) = 512 blocks, 256 thr (4 waves), 32 KB LDS.
// Wave w owns full-K chunk [w*256,(w+1)*256) — v5's exact per-wave summation
// order; LDS reduce (s0+s1)+(s2+s3) and argmax comparison identical to the
// proven v5 kernel -> idx bit-identical. No Lpart, no separate argmax phase.
// xb written by nh==0 blocks.
// ---------------------------------------------------------------------------
__global__ __launch_bounds__(256) void k_logits_mfma(
    const float* __restrict__ x, const ushort* __restrict__ cFh,
    const ushort* __restrict__ cFl, int* __restrict__ idx,
    ushort* __restrict__ xb)
{
    __shared__ float Lp[4 * 32 * 64];   // 32 KB
    const int g  = blockIdx.x >> 1;
    const int nh = blockIdx.x & 1;
    const int w = threadIdx.x >> 6;
    const int lane = threadIdx.x & 63;
    const int lrow = lane & 15;
    const int lk8 = (lane >> 4) * 8;

    const size_t xoff0 = ((size_t)g * TG + lrow) * DM + w * 256 + lk8;
    const float* xr0 = x + xoff0;
    const float* xr1 = xr0 + 16 * DM;

    f32x4 ahh[2][4], ax[2][4];
#pragma unroll
    for (int mt = 0; mt < 2; ++mt)
#pragma unroll
        for (int nt = 0; nt < 4; ++nt) {
            ahh[mt][nt] = (f32x4){0.f, 0.f, 0.f, 0.f};
            ax[mt][nt]  = (f32x4){0.f, 0.f, 0.f, 0.f};
        }

    for (int ks = 0; ks < 8; ++ks) {
        f16x8 Ah[2], Al[2];
#pragma unroll
        for (int mt = 0; mt < 2; ++mt) {
            const float* p = (mt ? xr1 : xr0) + ks * 32;
            float xe[8];
            *(float4*)&xe[0] = *(const float4*)p;
            *(float4*)&xe[4] = *(const float4*)(p + 4);
            union { f16x8 v; _Float16 e[8]; } H, L;
#pragma unroll
            for (int j = 0; j < 8; ++j) {
                const _Float16 h = (_Float16)xe[j];
                H.e[j] = h;
                L.e[j] = (_Float16)((xe[j] - (float)h) * LSCALE);
            }
            Ah[mt] = H.v; Al[mt] = L.v;
            if (nh == 0) {
                uint4 o;
                o.x = pk2(xe[0], xe[1]); o.y = pk2(xe[2], xe[3]);
                o.z = pk2(xe[4], xe[5]); o.w = pk2(xe[6], xe[7]);
                *(uint4*)(xb + xoff0 + (size_t)mt * 16 * DM + ks * 32) = o;
            }
        }
        const int kslice = w * 8 + ks;
#pragma unroll
        for (int nt = 0; nt < 4; ++nt) {
            const size_t fo = (((size_t)(nh * 4 + nt) * 32 + kslice) * 64 + lane) * 8;
            const f16x8 Bh = *(const f16x8*)(cFh + fo);
            const f16x8 Bl = *(const f16x8*)(cFl + fo);
#pragma unroll
            for (int mt = 0; mt < 2; ++mt) {
                ahh[mt][nt] = __builtin_amdgcn_mfma_f32_16x16x32_f16(Ah[mt], Bh, ahh[mt][nt], 0, 0, 0);
                ax[mt][nt]  = __builtin_amdgcn_mfma_f32_16x16x32_f16(Al[mt], Bh, ax[mt][nt], 0, 0, 0);
                ax[mt][nt]  = __builtin_amdgcn_mfma_f32_16x16x32_f16(Ah[mt], Bl, ax[mt][nt], 0, 0, 0);
            }
        }
    }

    // per-wave partials: row = mt*16 + (lane>>4)*4 + r, local col = nt*16 + lrow
#pragma unroll
    for (int mt = 0; mt < 2; ++mt)
#pragma unroll
        for (int nt = 0; nt < 4; ++nt)
#pragma unroll
            for (int r = 0; r < 4; ++r) {
                const int trow = mt * 16 + (lane >> 4) * 4 + r;
                const int nl = nt * 16 + lrow;
                Lp[(w * TG + trow) * 64 + nl] =
                    ahh[mt][nt][r] + ax[mt][nt][r] * INV_LSCALE;
            }
    __syncthreads();

    // reduce the 4 wave planes into plane 0 (same association as v5)
    for (int i = threadIdx.x * 4; i < TG * 64; i += 256 * 4) {
        f32x4 s0 = *(const f32x4*)&Lp[i];
        f32x4 s1 = *(const f32x4*)&Lp[2048 + i];
        f32x4 s2 = *(const f32x4*)&Lp[4096 + i];
        f32x4 s3 = *(const f32x4*)&Lp[6144 + i];
        *(f32x4*)&Lp[i] = (s0 + s1) + (s2 + s3);
    }
    __syncthreads();

    // fused tie-broken argmax (proven comparison code)
    if (threadIdx.x < 64) {
        const int n = threadIdx.x;
        float best = -1e30f;
        int bi = 0;
#pragma unroll
        for (int t = 0; t < TG; ++t) {
            const float v = Lp[t * 64 + n] + (float)t * (1e-6f / 31.0f);
            if (v >= best) { best = v; bi = t; }   // later token wins ties
        }
        idx[g * NSLOT + nh * 64 + n] = bi;
    }
}

// ---------------------------------------------------------------------------
// K2: H = relu(x_gathered @ f1 + bias) via MFMA. LDS-free (v6 form).
// grid = 128 es x 4 group-quarters = 512 blocks, 256 thr (4 waves).
// ---------------------------------------------------------------------------
__global__ __launch_bounds__(256) void k_h_mfma(
    const ushort* __restrict__ xb, const ushort* __restrict__ f1F,
    const float* __restrict__ bias, const int* __restrict__ idx,
    ushort* __restrict__ Hb)
{
    const int es = blockIdx.x >> 2;
    const int gq = blockIdx.x & 3;
    const int w = threadIdx.x >> 6;
    const int lane = threadIdx.x & 63;
    const int lrow = lane & 15;
    const int lk8 = (lane >> 4) * 8;

    const int ga = gq * 64 + w * 16 + lrow;
    const int tok = idx[ga * NSLOT + es];
    const ushort* abase = xb + ((size_t)ga * TG + tok) * DM + lk8;
    const ushort* bbase = f1F + (size_t)es * 2 * 32 * 512 + (size_t)lane * 8;

    f32x4 acc[2] = {(f32x4){0.f, 0.f, 0.f, 0.f}, (f32x4){0.f, 0.f, 0.f, 0.f}};

#pragma unroll 4
    for (int kslice = 0; kslice < 32; ++kslice) {
        const bf16x8 A = *(const bf16x8*)(abase + kslice * 32);
#pragma unroll
        for (int nt = 0; nt < 2; ++nt) {
            const bf16x8 B = *(const bf16x8*)(bbase + ((size_t)nt * 32 + kslice) * 512);
            acc[nt] = __builtin_amdgcn_mfma_f32_16x16x32_bf16(A, B, acc[nt], 0, 0, 0);
        }
    }

#pragma unroll
    for (int nt = 0; nt < 2; ++nt) {
        const int f = nt * 16 + lrow;
        const float bv = bias[es * FF + f];
#pragma unroll
        for (int r = 0; r < 4; ++r) {
            const int g = gq * 64 + w * 16 + (lane >> 4) * 4 + r;
            const float hv = fmaxf(acc[nt][r] + bv, 0.0f);
            Hb[(size_t)g * (NSLOT * FF) + es * FF + f] = f2bf(hv);
        }
    }
}

// ---------------------------------------------------------------------------
// K3: out accumulation via per-es MFMA + LDS scatter-accumulate.
// v8: the manual read-add-write chain is replaced by atomicAdd on LDS
// (ds_add_f32, fire-and-forget -> no dependent-latency chain; 2-way bank
// aliasing only). Unroll 4 now overlaps A/B loads + MFMAs across es.
// ---------------------------------------------------------------------------
__global__ __launch_bounds__(256) void k_out_mfma(
    const ushort* __restrict__ Hb, const ushort* __restrict__ f2T,
    const int* __restrict__ idx, float* __restrict__ out)
{
    extern __shared__ char smK3[];
    float* OL   = (float*)smK3;              // [16][2052] = 131328 B
    int* idxs_t = (int*)(smK3 + 131328);     // [128][16]  = 8192 B

    const int G0 = (blockIdx.x >> 4) * 16;
    const int D0 = (blockIdx.x & 15) * 64;
    const int tid = threadIdx.x;
    const int w = tid >> 6;
    const int lane = tid & 63;
    const int gl = lane & 15;
    const int lk8 = (lane >> 4) * 8;

    for (int i = tid * 4; i < 32768; i += 1024)
        *(f32x4*)&OL[i] = (f32x4){0.f, 0.f, 0.f, 0.f};
    if (tid < 16) *(f32x4*)&OL[32768 + tid * 4] = (f32x4){0.f, 0.f, 0.f, 0.f};
    for (int i = tid; i < NSLOT * 16; i += 256)
        idxs_t[i] = idx[(G0 + (i & 15)) * NSLOT + (i >> 4)];
    __syncthreads();

    const ushort* ap = f2T + (size_t)(D0 + w * 16 + gl) * FF + lk8;
    const ushort* bp = Hb + (size_t)(G0 + gl) * (NSLOT * FF) + lk8;
    const int dloc = w * 16 + (lane >> 4) * 4;
    float* olbase = &OL[gl * 2052 + dloc];

#pragma unroll 4
    for (int es = 0; es < NSLOT; ++es) {
        const bf16x8 afr = *(const bf16x8*)(ap + (size_t)es * (FF * DM));
        const bf16x8 bfr = *(const bf16x8*)(bp + es * FF);
        const f32x4 d = __builtin_amdgcn_mfma_f32_16x16x32_bf16(
            afr, bfr, (f32x4){0.f, 0.f, 0.f, 0.f}, 0, 0, 0);
        const int t = idxs_t[es * 16 + gl];
        float* olp = olbase + t * 64;
        atomicAdd(&olp[0], d[0]);
        atomicAdd(&olp[1], d[1]);
        atomicAdd(&olp[2], d[2]);
        atomicAdd(&olp[3], d[3]);
    }
    __syncthreads();

    for (int it = 0; it < 32; ++it) {
        const int flat = tid * 4 + it * 1024;
        const int gli = flat >> 11, rem = flat & 2047;
        const int t = rem >> 6, d = rem & 63;
        const f32x4 v = *(const f32x4*)&OL[gli * 2052 + rem];
        *(f32x4*)&out[((size_t)(G0 + gli) * TG + t) * DM + D0 + d] = v;
    }
}

// ---------------------------------------------------------------------------
extern "C" void kernel_launch(void* const* d_in, const int* in_sizes, int n_in,
                              void* d_out, int out_size, void* d_ws, size_t ws_size,
                              hipStream_t stream) {
    (void)in_sizes; (void)n_in; (void)out_size; (void)ws_size;
    const float* x    = (const float*)d_in[0];
    const float* ctrl = (const float*)d_in[1];
    const float* f1   = (const float*)d_in[2];
    const float* bias = (const float*)d_in[3];
    const float* f2   = (const float*)d_in[4];
    float* out = (float*)d_out;

    char* ws = (char*)d_ws;
    int*    idx   = (int*)ws;                       // 128 KB
    ushort* Hb    = (ushort*)(ws + 131072);         // 2 MB
    ushort* f1F   = (ushort*)(ws + 2228224);        // 8 MB
    ushort* f2T   = (ushort*)(ws + 10616832);       // 8 MB
    ushort* xb    = (ushort*)(ws + 19005440);       // 16 MB
    ushort* cFh   = (ushort*)(ws + 35782656);       // 256 KB
    ushort* cFl   = (ushort*)(ws + 36044800);       // 256 KB (end ~34.6 MB)

    k_prep<<<776, 256, 0, stream>>>(f1, f2, ctrl, f1F, f2T, cFh, cFl);

    k_logits_mfma<<<NGROUP * 2, 256, 0, stream>>>(x, cFh, cFl, idx, xb);

    k_h_mfma<<<NSLOT * 4, 256, 0, stream>>>(xb, f1F, bias, idx, Hb);

    const size_t lds3 = 131328 + 8192;              // 139520
    hipFuncSetAttribute((const void*)k_out_mfma,
                        hipFuncAttributeMaxDynamicSharedMemorySize, (int)lds3);
    k_out_mfma<<<256, 256, lds3, stream>>>(Hb, f2T, idx, out);
}

// Round 9
// 94.551 us; speedup vs baseline: 2.5272x; 2.5272x over previous
//
#include <hip/hip_runtime.h>
#include <hip/hip_bf16.h>

#define NGROUP 256   // B * (SEQ/TG)
#define NSLOT  128   // experts * sets
#define TG     32    // tokens per group
#define DM     1024  // model dim
#define FF     32    // expert size

#define LSCALE     4096.0f
#define INV_LSCALE (1.0f / 4096.0f)

typedef unsigned int  uint;
typedef unsigned short ushort;
typedef __attribute__((ext_vector_type(4))) float f32x4;
typedef __attribute__((ext_vector_type(8))) short bf16x8;
typedef __attribute__((ext_vector_type(8))) _Float16 f16x8;

__device__ __forceinline__ ushort f2bf(float f) {
    uint u = __float_as_uint(f);
    u += 0x7FFFu + ((u >> 16) & 1u);   // RNE
    return (ushort)(u >> 16);
}
__device__ __forceinline__ uint pk2(float a, float b) {
    return (uint)f2bf(a) | ((uint)f2bf(b) << 16);
}

// ---------------------------------------------------------------------------
// K1 mega-kernel: one launch, independent block families run concurrently.
//  blocks 0..511    : logits + tie-broken argmax + fused x->bf16 cast
//                     (ctrl read DIRECTLY in fp32, split in-register ->
//                      identical math + MFMA order as the proven cF path ->
//                      idx bit-identical; no prep dependency)
//  blocks 512..767  : f1[d][es][f] -> f1F bf16 (MFMA-B fragment order)
//  blocks 768..1279 : f2[es][f][d] -> f2T[es][d][f] bf16
// ---------------------------------------------------------------------------
__global__ __launch_bounds__(256) void k_fused1(
    const float* __restrict__ x, const float* __restrict__ ctrl,
    const float* __restrict__ f1, const float* __restrict__ f2,
    int* __restrict__ idx, ushort* __restrict__ xb,
    ushort* __restrict__ f1F, ushort* __restrict__ f2T)
{
    __shared__ float smem[4 * 32 * 64];   // 32 KB; logits: Lp, prep: Ltr alias
    const int t = threadIdx.x;

    if (blockIdx.x < 512) {
        // ---------------- logits + argmax (v8-proven structure) ----------
        float* Lp = smem;
        const int g  = blockIdx.x >> 1;
        const int nh = blockIdx.x & 1;
        const int w = t >> 6;
        const int lane = t & 63;
        const int lrow = lane & 15;
        const int lk8 = (lane >> 4) * 8;

        const size_t xoff0 = ((size_t)g * TG + lrow) * DM + w * 256 + lk8;
        const float* xr0 = x + xoff0;
        const float* xr1 = xr0 + 16 * DM;

        f32x4 ahh[2][4], ax[2][4];
#pragma unroll
        for (int mt = 0; mt < 2; ++mt)
#pragma unroll
            for (int nt = 0; nt < 4; ++nt) {
                ahh[mt][nt] = (f32x4){0.f, 0.f, 0.f, 0.f};
                ax[mt][nt]  = (f32x4){0.f, 0.f, 0.f, 0.f};
            }

        for (int ks = 0; ks < 8; ++ks) {
            f16x8 Ah[2], Al[2];
#pragma unroll
            for (int mt = 0; mt < 2; ++mt) {
                const float* p = (mt ? xr1 : xr0) + ks * 32;
                float xe[8];
                *(float4*)&xe[0] = *(const float4*)p;
                *(float4*)&xe[4] = *(const float4*)(p + 4);
                union { f16x8 v; _Float16 e[8]; } H, L;
#pragma unroll
                for (int j = 0; j < 8; ++j) {
                    const _Float16 h = (_Float16)xe[j];
                    H.e[j] = h;
                    L.e[j] = (_Float16)((xe[j] - (float)h) * LSCALE);
                }
                Ah[mt] = H.v; Al[mt] = L.v;
                if (nh == 0) {
                    uint4 o;
                    o.x = pk2(xe[0], xe[1]); o.y = pk2(xe[2], xe[3]);
                    o.z = pk2(xe[4], xe[5]); o.w = pk2(xe[6], xe[7]);
                    *(uint4*)(xb + xoff0 + (size_t)mt * 16 * DM + ks * 32) = o;
                }
            }
            const int kslice = w * 8 + ks;
#pragma unroll
            for (int nt = 0; nt < 4; ++nt) {
                // ctrl fragment, read directly: k = kslice*32+(lane>>4)*8+j,
                // n = nh*64 + nt*16 + (lane&15); same per-element split math
                // as the old prep -> bit-identical fragments.
                const float* cp = ctrl
                    + (size_t)(kslice * 32 + ((lane >> 4) << 3)) * NSLOT
                    + nh * 64 + nt * 16 + (lane & 15);
                union { f16x8 v; _Float16 e[8]; } BH, BL;
#pragma unroll
                for (int j = 0; j < 8; ++j) {
                    const float c = cp[(size_t)j * NSLOT];
                    const _Float16 h = (_Float16)c;
                    BH.e[j] = h;
                    BL.e[j] = (_Float16)((c - (float)h) * LSCALE);
                }
#pragma unroll
                for (int mt = 0; mt < 2; ++mt) {
                    ahh[mt][nt] = __builtin_amdgcn_mfma_f32_16x16x32_f16(Ah[mt], BH.v, ahh[mt][nt], 0, 0, 0);
                    ax[mt][nt]  = __builtin_amdgcn_mfma_f32_16x16x32_f16(Al[mt], BH.v, ax[mt][nt], 0, 0, 0);
                    ax[mt][nt]  = __builtin_amdgcn_mfma_f32_16x16x32_f16(Ah[mt], BL.v, ax[mt][nt], 0, 0, 0);
                }
            }
        }

#pragma unroll
        for (int mt = 0; mt < 2; ++mt)
#pragma unroll
            for (int nt = 0; nt < 4; ++nt)
#pragma unroll
                for (int r = 0; r < 4; ++r) {
                    const int trow = mt * 16 + (lane >> 4) * 4 + r;
                    const int nl = nt * 16 + lrow;
                    Lp[(w * TG + trow) * 64 + nl] =
                        ahh[mt][nt][r] + ax[mt][nt][r] * INV_LSCALE;
                }
        __syncthreads();

        for (int i = t * 4; i < TG * 64; i += 256 * 4) {
            f32x4 s0 = *(const f32x4*)&Lp[i];
            f32x4 s1 = *(const f32x4*)&Lp[2048 + i];
            f32x4 s2 = *(const f32x4*)&Lp[4096 + i];
            f32x4 s3 = *(const f32x4*)&Lp[6144 + i];
            *(f32x4*)&Lp[i] = (s0 + s1) + (s2 + s3);
        }
        __syncthreads();

        if (t < 64) {
            const int n = t;
            float best = -1e30f;
            int bi = 0;
#pragma unroll
            for (int tt = 0; tt < TG; ++tt) {
                const float v = Lp[tt * 64 + n] + (float)tt * (1e-6f / 31.0f);
                if (v >= best) { best = v; bi = tt; }   // later token wins ties
            }
            idx[g * NSLOT + nh * 64 + n] = bi;
        }
    } else if (blockIdx.x < 768) {
        // ---------------- f1 -> f1F fragment-order transpose -------------
        float* Ltr = smem;   // [64][33]
        const int i1 = blockIdx.x - 512;
        const int es = i1 >> 1;
        const int dh = i1 & 1;
        for (int d0 = dh * 512; d0 < dh * 512 + 512; d0 += 64) {
            const int dd = t >> 2, f0 = (t & 3) * 8;
            const float* src = f1 + (size_t)(d0 + dd) * 4096 + es * FF + f0;
            float4 a = *(const float4*)src;
            float4 b = *(const float4*)(src + 4);
            __syncthreads();
            float* Lq = &Ltr[dd * 33 + f0];
            Lq[0] = a.x; Lq[1] = a.y; Lq[2] = a.z; Lq[3] = a.w;
            Lq[4] = b.x; Lq[5] = b.y; Lq[6] = b.z; Lq[7] = b.w;
            __syncthreads();
            const int f = t & 31, koct = t >> 5;
            const int nt = f >> 4;
            const int kg = d0 + koct * 8;
            const int kslice = kg >> 5;
            const int lane2 = (f & 15) | (((kg >> 3) & 3) << 4);
            uint4 o;
            o.x = pk2(Ltr[(koct * 8 + 0) * 33 + f], Ltr[(koct * 8 + 1) * 33 + f]);
            o.y = pk2(Ltr[(koct * 8 + 2) * 33 + f], Ltr[(koct * 8 + 3) * 33 + f]);
            o.z = pk2(Ltr[(koct * 8 + 4) * 33 + f], Ltr[(koct * 8 + 5) * 33 + f]);
            o.w = pk2(Ltr[(koct * 8 + 6) * 33 + f], Ltr[(koct * 8 + 7) * 33 + f]);
            *(uint4*)(f1F + ((((size_t)es * 2 + nt) * 32 + kslice) * 64 + lane2) * 8) = o;
        }
    } else {
        // ---------------- f2 -> f2T transpose -----------------------------
        float* Ltr = smem;   // [64][33]
        const int i2 = blockIdx.x - 768;
        const int es = i2 >> 2;
        const int dq = i2 & 3;
        for (int d0 = dq * 256; d0 < dq * 256 + 256; d0 += 64) {
            const int f = t >> 3, ds = (t & 7) * 8;
            const float* src = f2 + (size_t)es * (FF * DM) + f * DM + d0 + ds;
            float4 a = *(const float4*)src;
            float4 b = *(const float4*)(src + 4);
            __syncthreads();
            Ltr[(ds + 0) * 33 + f] = a.x; Ltr[(ds + 1) * 33 + f] = a.y;
            Ltr[(ds + 2) * 33 + f] = a.z; Ltr[(ds + 3) * 33 + f] = a.w;
            Ltr[(ds + 4) * 33 + f] = b.x; Ltr[(ds + 5) * 33 + f] = b.y;
            Ltr[(ds + 6) * 33 + f] = b.z; Ltr[(ds + 7) * 33 + f] = b.w;
            __syncthreads();
            const int dd = t >> 2, f0 = (t & 3) * 8;
            uint4 o;
            o.x = pk2(Ltr[dd * 33 + f0 + 0], Ltr[dd * 33 + f0 + 1]);
            o.y = pk2(Ltr[dd * 33 + f0 + 2], Ltr[dd * 33 + f0 + 3]);
            o.z = pk2(Ltr[dd * 33 + f0 + 4], Ltr[dd * 33 + f0 + 5]);
            o.w = pk2(Ltr[dd * 33 + f0 + 6], Ltr[dd * 33 + f0 + 7]);
            *(uint4*)(f2T + (size_t)es * (FF * DM) + (d0 + dd) * FF + f0) = o;
        }
    }
}

// ---------------------------------------------------------------------------
// K2: H = relu(x_gathered @ f1 + bias) via MFMA. LDS-free. UNCHANGED.
// grid = 128 es x 4 group-quarters = 512 blocks, 256 thr (4 waves).
// ---------------------------------------------------------------------------
__global__ __launch_bounds__(256) void k_h_mfma(
    const ushort* __restrict__ xb, const ushort* __restrict__ f1F,
    const float* __restrict__ bias, const int* __restrict__ idx,
    ushort* __restrict__ Hb)
{
    const int es = blockIdx.x >> 2;
    const int gq = blockIdx.x & 3;
    const int w = threadIdx.x >> 6;
    const int lane = threadIdx.x & 63;
    const int lrow = lane & 15;
    const int lk8 = (lane >> 4) * 8;

    const int ga = gq * 64 + w * 16 + lrow;
    const int tok = idx[ga * NSLOT + es];
    const ushort* abase = xb + ((size_t)ga * TG + tok) * DM + lk8;
    const ushort* bbase = f1F + (size_t)es * 2 * 32 * 512 + (size_t)lane * 8;

    f32x4 acc[2] = {(f32x4){0.f, 0.f, 0.f, 0.f}, (f32x4){0.f, 0.f, 0.f, 0.f}};

#pragma unroll 4
    for (int kslice = 0; kslice < 32; ++kslice) {
        const bf16x8 A = *(const bf16x8*)(abase + kslice * 32);
#pragma unroll
        for (int nt = 0; nt < 2; ++nt) {
            const bf16x8 B = *(const bf16x8*)(bbase + ((size_t)nt * 32 + kslice) * 512);
            acc[nt] = __builtin_amdgcn_mfma_f32_16x16x32_bf16(A, B, acc[nt], 0, 0, 0);
        }
    }

#pragma unroll
    for (int nt = 0; nt < 2; ++nt) {
        const int f = nt * 16 + lrow;
        const float bv = bias[es * FF + f];
#pragma unroll
        for (int r = 0; r < 4; ++r) {
            const int g = gq * 64 + w * 16 + (lane >> 4) * 4 + r;
            const float hv = fmaxf(acc[nt][r] + bv, 0.0f);
            Hb[(size_t)g * (NSLOT * FF) + es * FF + f] = f2bf(hv);
        }
    }
}

// ---------------------------------------------------------------------------
// K3: out accumulation, register-RMW form (v7-proven), 8 groups per block.
// grid = 32 group-octets x 16 d-blocks = 512 blocks, ~70 KB LDS -> 2/CU.
// MFMA B duplicates group (n&7) in cols n and n+8: duplicate lanes RMW the
// same LDS address with identical values within one SIMD instruction (all
// lanes read old, all write old+d) -> benign, result correct.
// ---------------------------------------------------------------------------
__global__ __launch_bounds__(256) void k_out_mfma(
    const ushort* __restrict__ Hb, const ushort* __restrict__ f2T,
    const int* __restrict__ idx, float* __restrict__ out)
{
    extern __shared__ char smK3[];
    float* OL   = (float*)smK3;              // [8][2052] = 65664 B
    int* idxs_t = (int*)(smK3 + 65664);      // [128][8]  = 4096 B

    const int G0 = (blockIdx.x >> 4) * 8;
    const int D0 = (blockIdx.x & 15) * 64;
    const int tid = threadIdx.x;
    const int w = tid >> 6;
    const int lane = tid & 63;
    const int gl = lane & 15;
    const int g8 = gl & 7;
    const int lk8 = (lane >> 4) * 8;

    for (int i = tid * 4; i < 8 * 2052; i += 1024)
        *(f32x4*)&OL[i] = (f32x4){0.f, 0.f, 0.f, 0.f};
    for (int i = tid; i < NSLOT * 8; i += 256)
        idxs_t[i] = idx[(G0 + (i & 7)) * NSLOT + (i >> 3)];
    __syncthreads();

    // A: f2T[es][d][f], d = D0 + w*16 + gl (full 16 rows, M=16 d)
    // B: Hb rows for 8 groups, duplicated across cols n / n+8
    const ushort* ap = f2T + (size_t)(D0 + w * 16 + gl) * FF + lk8;
    const ushort* bp = Hb + (size_t)(G0 + g8) * (NSLOT * FF) + lk8;
    const int dloc = w * 16 + (lane >> 4) * 4;
    float* olbase = &OL[g8 * 2052 + dloc];

#pragma unroll 4
    for (int es = 0; es < NSLOT; ++es) {
        const bf16x8 afr = *(const bf16x8*)(ap + (size_t)es * (FF * DM));
        const bf16x8 bfr = *(const bf16x8*)(bp + es * FF);
        const f32x4 d = __builtin_amdgcn_mfma_f32_16x16x32_bf16(
            afr, bfr, (f32x4){0.f, 0.f, 0.f, 0.f}, 0, 0, 0);
        const int t = idxs_t[es * 8 + g8];
        float* olp = olbase + t * 64;
        *(f32x4*)olp = *(const f32x4*)olp + d;
    }
    __syncthreads();

    // dense write-out: 8 groups x 32 t x 64 d = 16384 f32
    for (int it = 0; it < 16; ++it) {
        const int flat = tid * 4 + it * 1024;
        const int gli = flat >> 11, rem = flat & 2047;
        const int t = rem >> 6, d = rem & 63;
        const f32x4 v = *(const f32x4*)&OL[gli * 2052 + rem];
        *(f32x4*)&out[((size_t)(G0 + gli) * TG + t) * DM + D0 + d] = v;
    }
}

// ---------------------------------------------------------------------------
extern "C" void kernel_launch(void* const* d_in, const int* in_sizes, int n_in,
                              void* d_out, int out_size, void* d_ws, size_t ws_size,
                              hipStream_t stream) {
    (void)in_sizes; (void)n_in; (void)out_size; (void)ws_size;
    const float* x    = (const float*)d_in[0];
    const float* ctrl = (const float*)d_in[1];
    const float* f1   = (const float*)d_in[2];
    const float* bias = (const float*)d_in[3];
    const float* f2   = (const float*)d_in[4];
    float* out = (float*)d_out;

    char* ws = (char*)d_ws;
    int*    idx = (int*)ws;                         // 128 KB
    ushort* Hb  = (ushort*)(ws + 131072);           // 2 MB
    ushort* f1F = (ushort*)(ws + 2228224);          // 8 MB
    ushort* f2T = (ushort*)(ws + 10616832);         // 8 MB
    ushort* xb  = (ushort*)(ws + 19005440);         // 16 MB (end ~34 MB)

    k_fused1<<<1280, 256, 0, stream>>>(x, ctrl, f1, f2, idx, xb, f1F, f2T);

    k_h_mfma<<<NSLOT * 4, 256, 0, stream>>>(xb, f1F, bias, idx, Hb);

    const size_t lds3 = 65664 + 4096;               // 69760 -> 2 blocks/CU
    hipFuncSetAttribute((const void*)k_out_mfma,
                        hipFuncAttributeMaxDynamicSharedMemorySize, (int)lds3);
    k_out_mfma<<<512, 256, lds3, stream>>>(Hb, f2T, idx, out);
}